// Round 2
// baseline (651.215 us; speedup 1.0000x reference)
//
#include <hip/hip_runtime.h>
#include <math.h>

// Problem constants (from reference)
#define NROWS 32768   // N
#define DD 32         // D
#define PPH 16        // P
#define HH 256        // H
#define BB 65536      // B
#define K1 512        // P*D
#define W3 768        // 3*H
#define TWO_LOG_C 1.8378770664093453f

// ---------------------------------------------------------------------------
// Kernel 1: elementwise prep. For each (n,d):
//   mean/logvar from p[i_obs[n]], error, losses -> out
//   G[q][n][d] = relu([x,mean,logvar,err] . w_prep[d,:,q] + bias_prep[d,q]) * M
// G is the [P,N,D] C-order array == GRU input X[N,512] row-major.
// ---------------------------------------------------------------------------
__global__ __launch_bounds__(256) void prep_kernel(
    const float* __restrict__ p,
    const float* __restrict__ X_obs,
    const float* __restrict__ M_obs,
    const int*   __restrict__ i_obs,
    const float* __restrict__ w_prep,    // [D,4,P]
    const float* __restrict__ bias_prep, // [D,P]
    float* __restrict__ losses_out,      // [N,D]
    float* __restrict__ G)               // [P,N,D] f32
{
    __shared__ float w_s[DD * 4 * PPH];   // 2048
    __shared__ float b_s[DD * PPH];       // 512
    int tid = threadIdx.x;
    for (int i = tid; i < DD * 4 * PPH; i += 256) w_s[i] = w_prep[i];
    for (int i = tid; i < DD * PPH; i += 256) b_s[i] = bias_prep[i];
    __syncthreads();

    int gid = blockIdx.x * 256 + tid;     // covers N*D exactly (4096 blocks)
    int n = gid >> 5;
    int d = gid & 31;
    int idx = i_obs[n];

    float mean   = p[idx * (2 * DD) + d];
    float logvar = p[idx * (2 * DD) + DD + d];
    float x      = X_obs[gid];
    float m      = M_obs[gid];

    float inv_sigma = expf(-0.5f * logvar);
    float err = (x - mean) * inv_sigma;
    losses_out[gid] = 0.5f * ((err * err + logvar + TWO_LOG_C) * m);

    const float* wd = &w_s[d * 64];
    const float* bd = &b_s[d * PPH];
    #pragma unroll
    for (int q = 0; q < PPH; ++q) {
        float v = x      * wd[0 * PPH + q]
                + mean   * wd[1 * PPH + q]
                + logvar * wd[2 * PPH + q]
                + err    * wd[3 * PPH + q]
                + bd[q];
        v = fmaxf(v, 0.0f) * m;
        G[(size_t)q * (NROWS * DD) + gid] = v;
    }
}

// ---------------------------------------------------------------------------
// Kernel 2: copy h -> h_out (all B rows; scattered rows overwritten later)
// ---------------------------------------------------------------------------
__global__ __launch_bounds__(256) void copy_h_kernel(
    const float4* __restrict__ h, float4* __restrict__ out, int n4)
{
    int i = blockIdx.x * 256 + threadIdx.x;
    int stride = gridDim.x * 256;
    for (; i < n4; i += stride) out[i] = h[i];
}

// ---------------------------------------------------------------------------
// Kernel 3: fused GRU. Per 64x64 tile (rows of N, cols of H):
//   phase1: X(=G)[N,512] @ gru_kernel cols {j, 256+j, 512+j} -> az, ar, axh
//   phase2: h[i_obs][N,256] @ rec_kernel cols {j, 256+j, 512+j} -> az+=, ar+=, arh
//   gates + scatter-write h_out[i_obs[i]]
// ---------------------------------------------------------------------------
#define BM 64
#define BN 64
#define KT 16

__global__ __launch_bounds__(256) void gru_kernel(
    const float* __restrict__ G,        // [N, 512] row-major
    const float* __restrict__ h,        // [B, 256]
    const int*   __restrict__ i_obs,
    const float* __restrict__ Kmat,     // [512, 768]
    const float* __restrict__ Rmat,     // [256, 768]
    const float* __restrict__ bias_in,  // [768]
    const float* __restrict__ bias_rec, // [768]
    float* __restrict__ h_out)          // [B, 256]
{
    __shared__ float As[KT][68];        // padded: stride 68 (4-aligned, bank-spread)
    __shared__ float Bzs[KT][64];
    __shared__ float Brs[KT][64];
    __shared__ float Bhs[KT][64];
    __shared__ int idx_s[BM];

    int tid = threadIdx.x;
    int tx = tid & 15, ty = tid >> 4;
    int i0 = blockIdx.y * BM;
    int j0 = blockIdx.x * BN;

    if (tid < BM) idx_s[tid] = i_obs[i0 + tid];

    float az[4][4] = {{0}}, ar[4][4] = {{0}}, axh[4][4] = {{0}}, arh[4][4] = {{0}};
    __syncthreads();

    // ---- phase 1: K = 512 over X = G ----
    for (int k0 = 0; k0 < K1; k0 += KT) {
        {
            int kk = tid & 15, ii0 = tid >> 4;
            #pragma unroll
            for (int rep = 0; rep < 4; ++rep) {
                int ii = ii0 + rep * 16;
                As[kk][ii] = G[(size_t)(i0 + ii) * K1 + k0 + kk];
            }
        }
        {
            int jj = tid & 63, kk0 = tid >> 6;
            #pragma unroll
            for (int rep = 0; rep < 4; ++rep) {
                int kk = kk0 + rep * 4;
                const float* brow = Kmat + (size_t)(k0 + kk) * W3;
                Bzs[kk][jj] = brow[j0 + jj];
                Brs[kk][jj] = brow[256 + j0 + jj];
                Bhs[kk][jj] = brow[512 + j0 + jj];
            }
        }
        __syncthreads();
        #pragma unroll
        for (int kk = 0; kk < KT; ++kk) {
            float a[4], bz[4], br[4], bh[4];
            #pragma unroll
            for (int r = 0; r < 4; ++r) a[r] = As[kk][ty * 4 + r];
            #pragma unroll
            for (int c = 0; c < 4; ++c) {
                bz[c] = Bzs[kk][tx * 4 + c];
                br[c] = Brs[kk][tx * 4 + c];
                bh[c] = Bhs[kk][tx * 4 + c];
            }
            #pragma unroll
            for (int r = 0; r < 4; ++r)
                #pragma unroll
                for (int c = 0; c < 4; ++c) {
                    az[r][c]  = fmaf(a[r], bz[c], az[r][c]);
                    ar[r][c]  = fmaf(a[r], br[c], ar[r][c]);
                    axh[r][c] = fmaf(a[r], bh[c], axh[r][c]);
                }
        }
        __syncthreads();
    }

    // ---- phase 2: K = 256 over h_obs ----
    for (int k0 = 0; k0 < HH; k0 += KT) {
        {
            int kk = tid & 15, ii0 = tid >> 4;
            #pragma unroll
            for (int rep = 0; rep < 4; ++rep) {
                int ii = ii0 + rep * 16;
                As[kk][ii] = h[(size_t)idx_s[ii] * HH + k0 + kk];
            }
        }
        {
            int jj = tid & 63, kk0 = tid >> 6;
            #pragma unroll
            for (int rep = 0; rep < 4; ++rep) {
                int kk = kk0 + rep * 4;
                const float* brow = Rmat + (size_t)(k0 + kk) * W3;
                Bzs[kk][jj] = brow[j0 + jj];
                Brs[kk][jj] = brow[256 + j0 + jj];
                Bhs[kk][jj] = brow[512 + j0 + jj];
            }
        }
        __syncthreads();
        #pragma unroll
        for (int kk = 0; kk < KT; ++kk) {
            float a[4], bz[4], br[4], bh[4];
            #pragma unroll
            for (int r = 0; r < 4; ++r) a[r] = As[kk][ty * 4 + r];
            #pragma unroll
            for (int c = 0; c < 4; ++c) {
                bz[c] = Bzs[kk][tx * 4 + c];
                br[c] = Brs[kk][tx * 4 + c];
                bh[c] = Bhs[kk][tx * 4 + c];
            }
            #pragma unroll
            for (int r = 0; r < 4; ++r)
                #pragma unroll
                for (int c = 0; c < 4; ++c) {
                    az[r][c]  = fmaf(a[r], bz[c], az[r][c]);
                    ar[r][c]  = fmaf(a[r], br[c], ar[r][c]);
                    arh[r][c] = fmaf(a[r], bh[c], arh[r][c]);
                }
        }
        __syncthreads();
    }

    // ---- epilogue: gates + scatter ----
    #pragma unroll
    for (int c = 0; c < 4; ++c) {
        int j = j0 + tx * 4 + c;
        float bz  = bias_in[j]       + bias_rec[j];
        float brr = bias_in[256 + j] + bias_rec[256 + j];
        float bxh = bias_in[512 + j];
        float brh = bias_rec[512 + j];
        #pragma unroll
        for (int r = 0; r < 4; ++r) {
            int idx = idx_s[ty * 4 + r];
            float z  = 1.0f / (1.0f + expf(-(az[r][c] + bz)));
            float rr = 1.0f / (1.0f + expf(-(ar[r][c] + brr)));
            float hh = tanhf(axh[r][c] + bxh + rr * (arh[r][c] + brh));
            float hprev = h[(size_t)idx * HH + j];
            h_out[(size_t)idx * HH + j] = z * hprev + (1.0f - z) * hh;
        }
    }
}

// ---------------------------------------------------------------------------
extern "C" void kernel_launch(void* const* d_in, const int* in_sizes, int n_in,
                              void* d_out, int out_size, void* d_ws, size_t ws_size,
                              hipStream_t stream) {
    const float* h         = (const float*)d_in[0];
    const float* p         = (const float*)d_in[1];
    const float* X_obs     = (const float*)d_in[2];
    const float* M_obs     = (const float*)d_in[3];
    const int*   i_obs     = (const int*)  d_in[4];
    const float* w_prep    = (const float*)d_in[5];
    const float* bias_prep = (const float*)d_in[6];
    const float* gk        = (const float*)d_in[7];
    const float* grk       = (const float*)d_in[8];
    const float* gbi       = (const float*)d_in[9];
    const float* gbr       = (const float*)d_in[10];

    float* out    = (float*)d_out;
    float* h_out  = out;                        // [B,H]
    float* losses = out + (size_t)BB * HH;      // [N,D]
    float* G      = (float*)d_ws;               // [P,N,D] f32 = 64 MiB

    // 1) prep + losses + build G
    prep_kernel<<<(NROWS * DD) / 256, 256, 0, stream>>>(
        p, X_obs, M_obs, i_obs, w_prep, bias_prep, losses, G);

    // 2) copy h -> h_out
    copy_h_kernel<<<2048, 256, 0, stream>>>(
        (const float4*)h, (float4*)h_out, BB * HH / 4);

    // 3) fused GRU GEMMs + gates + scatter
    dim3 grid(HH / BN, NROWS / BM);
    gru_kernel<<<grid, 256, 0, stream>>>(
        G, h, i_obs, gk, grk, gbi, gbr, h_out);
}

// Round 4
// 286.144 us; speedup vs baseline: 2.2758x; 2.2758x over previous
//
#include <hip/hip_runtime.h>
#include <hip/hip_bf16.h>
#include <math.h>

// Problem constants
#define NROWS 32768   // N (GRU batch rows)
#define DD 32         // D
#define PPH 16        // P
#define HH 256        // H
#define BB 65536      // B
#define TWO_LOG_C 1.8378770664093453f

typedef __attribute__((ext_vector_type(8))) __bf16 bf16x8;
typedef __attribute__((ext_vector_type(4))) float f32x4;

__device__ __forceinline__ float sigm_f(float x) { return 1.0f / (1.0f + __expf(-x)); }
__device__ __forceinline__ float tanh_f(float x) { return 1.0f - 2.0f / (1.0f + __expf(2.0f * x)); }

// ---------------------------------------------------------------------------
// Kernel 1: elementwise prep -> losses (f32) + G (bf16, [P,N,D] flat = GRU
// input rows [N,512] row-major).
// ---------------------------------------------------------------------------
__global__ __launch_bounds__(256) void prep_kernel(
    const float* __restrict__ p,
    const float* __restrict__ X_obs,
    const float* __restrict__ M_obs,
    const int*   __restrict__ i_obs,
    const float* __restrict__ w_prep,    // [D,4,P]
    const float* __restrict__ bias_prep, // [D,P]
    float* __restrict__ losses_out,      // [N,D]
    __bf16* __restrict__ G)              // [N,512] bf16
{
    __shared__ float w_s[DD * 4 * PPH];
    __shared__ float b_s[DD * PPH];
    int tid = threadIdx.x;
    for (int i = tid; i < DD * 4 * PPH; i += 256) w_s[i] = w_prep[i];
    for (int i = tid; i < DD * PPH; i += 256) b_s[i] = bias_prep[i];
    __syncthreads();

    int gid = blockIdx.x * 256 + tid;
    int n = gid >> 5;
    int d = gid & 31;
    int idx = i_obs[n];

    float mean   = p[idx * (2 * DD) + d];
    float logvar = p[idx * (2 * DD) + DD + d];
    float x      = X_obs[gid];
    float m      = M_obs[gid];

    float inv_sigma = __expf(-0.5f * logvar);
    float err = (x - mean) * inv_sigma;
    losses_out[gid] = 0.5f * ((err * err + logvar + TWO_LOG_C) * m);

    const float* wd = &w_s[d * 64];
    const float* bd = &b_s[d * PPH];
    #pragma unroll
    for (int q = 0; q < PPH; ++q) {
        float v = x      * wd[0 * PPH + q]
                + mean   * wd[1 * PPH + q]
                + logvar * wd[2 * PPH + q]
                + err    * wd[3 * PPH + q]
                + bd[q];
        v = fmaxf(v, 0.0f) * m;
        G[(size_t)q * (NROWS * DD) + gid] = (__bf16)v;
    }
}

// ---------------------------------------------------------------------------
// Kernel 2: copy h -> h_out (scattered rows overwritten later by gru kernel)
// ---------------------------------------------------------------------------
__global__ __launch_bounds__(256) void copy_h_kernel(
    const float4* __restrict__ h, float4* __restrict__ out, int n4)
{
    int i = blockIdx.x * 256 + threadIdx.x;
    int stride = gridDim.x * 256;
    for (; i < n4; i += stride) out[i] = h[i];
}

// ---------------------------------------------------------------------------
// Kernel 3: weight transpose + f32->bf16:  dst[j][k] = (bf16)src[k][j]
// src is [K][768]; dst is [768][K]. 64x64 tiles via LDS.
// ---------------------------------------------------------------------------
__global__ __launch_bounds__(256) void transpose_w_kernel(
    const float* __restrict__ src, __bf16* __restrict__ dst, int K)
{
    __shared__ float t[64][65];
    int k0 = blockIdx.x * 64;
    int j0 = blockIdx.y * 64;
    int tx = threadIdx.x & 63, ty = threadIdx.x >> 6;  // ty 0..3
    #pragma unroll
    for (int i = 0; i < 16; ++i) {
        int k = ty * 16 + i;
        t[k][tx] = src[(size_t)(k0 + k) * 768 + j0 + tx];
    }
    __syncthreads();
    #pragma unroll
    for (int i = 0; i < 16; ++i) {
        int j = ty * 16 + i;
        dst[(size_t)(j0 + j) * K + k0 + tx] = (__bf16)t[tx][j];
    }
}

// ---------------------------------------------------------------------------
// Kernel 4: fused GRU via bf16 MFMA.
// Block: 128 rows x 64 j-cols, 4 waves (2 row-halves x 2 col-halves).
// Wave tile: 64 rows (Mrep=4) x 32 j (Nrep=2); acc sets: az, ar, axh, arh.
// LDS (linear, conflict-free): A [4 kgrp][128 row][8] bf16 (8KB),
//                              B [3 mat][4 kgrp][64 j][8] bf16 (12KB).
// Phase1: A=G bf16 (K=512, weights Kt). Phase2: A=h[i_obs] f32->bf16 (K=256, Rt).
// Epilogue: gates + scatter into h_out.
// ---------------------------------------------------------------------------
__global__ __launch_bounds__(256, 2) void gru_mfma_kernel(
    const __bf16* __restrict__ G,     // [N,512]
    const float*  __restrict__ h,     // [B,256]
    const int*    __restrict__ i_obs, // [N]
    const __bf16* __restrict__ Kt,    // [768][512]
    const __bf16* __restrict__ Rt,    // [768][256]
    const float*  __restrict__ bi,    // bias_in [768]
    const float*  __restrict__ brc,   // bias_rec [768]
    float* __restrict__ h_out)        // [B,256]
{
    __shared__ char smem[20992] __attribute__((aligned(128)));
    __bf16* ldsA = (__bf16*)smem;              // [4][128][8]
    __bf16* ldsB = (__bf16*)(smem + 8192);     // [3][4][64][8]
    int* idx_s   = (int*)(smem + 20480);       // [128]

    const int tid  = threadIdx.x;
    const int lane = tid & 63;
    const int wave = tid >> 6;
    const int lrow = lane & 15;
    const int kgrp = lane >> 4;
    const int rw = wave >> 1;   // row half
    const int cw = wave & 1;    // col half

    // XCD-aware swizzle (1024 blocks, 8 XCDs): same-row-panel j-quartet lands
    // on one XCD, close in dispatch time -> G/h panels read once per XCD L2.
    int bid = blockIdx.x;
    int swz = (bid & 7) * 128 + (bid >> 3);
    const int i0 = (swz >> 2) * 128;
    const int j0 = (swz & 3) * 64;

    if (tid < 128) idx_s[tid] = i_obs[i0 + tid];

    f32x4 az[4][2], ar[4][2], axh[4][2], arh[4][2];
    const f32x4 zero4 = {0.f, 0.f, 0.f, 0.f};
    #pragma unroll
    for (int m = 0; m < 4; ++m)
        #pragma unroll
        for (int j = 0; j < 2; ++j) {
            az[m][j] = zero4; ar[m][j] = zero4; axh[m][j] = zero4; arh[m][j] = zero4;
        }

    // staging slot decomposition (512 16B slots for A, 256/mat for B)
    const int arow = tid & 127;
    const int akg  = tid >> 7;          // 0/1 (second slot uses akg+2)
    const int bj   = tid & 63;
    const int bkg  = tid >> 6;          // 0..3

    const __bf16* gA  = G + (size_t)(i0 + arow) * 512;
    const __bf16* kB0 = Kt + (size_t)(      j0 + bj) * 512 + bkg * 8;
    const __bf16* kB1 = Kt + (size_t)(256 + j0 + bj) * 512 + bkg * 8;
    const __bf16* kB2 = Kt + (size_t)(512 + j0 + bj) * 512 + bkg * 8;

    // ---- phase 1: K=512, A from G, weights Kt ----
    for (int k0 = 0; k0 < 512; k0 += 32) {
        bf16x8 av0 = *(const bf16x8*)(gA + k0 + akg * 8);
        bf16x8 av1 = *(const bf16x8*)(gA + k0 + (akg + 2) * 8);
        bf16x8 bv0 = *(const bf16x8*)(kB0 + k0);
        bf16x8 bv1 = *(const bf16x8*)(kB1 + k0);
        bf16x8 bv2 = *(const bf16x8*)(kB2 + k0);
        __syncthreads();   // previous compute done reading LDS
        *(bf16x8*)(ldsA + ((akg)     * 128 + arow) * 8) = av0;
        *(bf16x8*)(ldsA + ((akg + 2) * 128 + arow) * 8) = av1;
        *(bf16x8*)(ldsB + (0 * 256 + bkg * 64 + bj) * 8) = bv0;
        *(bf16x8*)(ldsB + (1 * 256 + bkg * 64 + bj) * 8) = bv1;
        *(bf16x8*)(ldsB + (2 * 256 + bkg * 64 + bj) * 8) = bv2;
        __syncthreads();   // staged data visible

        bf16x8 af[4], bz[2], brf[2], bh[2];
        #pragma unroll
        for (int mt = 0; mt < 4; ++mt)
            af[mt] = *(const bf16x8*)(ldsA + (kgrp * 128 + rw * 64 + mt * 16 + lrow) * 8);
        #pragma unroll
        for (int jt = 0; jt < 2; ++jt) {
            int jj = cw * 32 + jt * 16 + lrow;
            bz[jt]  = *(const bf16x8*)(ldsB + (0 * 256 + kgrp * 64 + jj) * 8);
            brf[jt] = *(const bf16x8*)(ldsB + (1 * 256 + kgrp * 64 + jj) * 8);
            bh[jt]  = *(const bf16x8*)(ldsB + (2 * 256 + kgrp * 64 + jj) * 8);
        }
        #pragma unroll
        for (int mt = 0; mt < 4; ++mt)
            #pragma unroll
            for (int jt = 0; jt < 2; ++jt) {
                az[mt][jt]  = __builtin_amdgcn_mfma_f32_16x16x32_bf16(af[mt], bz[jt],  az[mt][jt],  0, 0, 0);
                ar[mt][jt]  = __builtin_amdgcn_mfma_f32_16x16x32_bf16(af[mt], brf[jt], ar[mt][jt],  0, 0, 0);
                axh[mt][jt] = __builtin_amdgcn_mfma_f32_16x16x32_bf16(af[mt], bh[jt],  axh[mt][jt], 0, 0, 0);
            }
    }

    // ---- phase 2: K=256, A = h[i_obs] (f32 -> bf16 inline), weights Rt ----
    const float* hA = h + (size_t)idx_s[arow] * 256;
    const __bf16* rB0 = Rt + (size_t)(      j0 + bj) * 256 + bkg * 8;
    const __bf16* rB1 = Rt + (size_t)(256 + j0 + bj) * 256 + bkg * 8;
    const __bf16* rB2 = Rt + (size_t)(512 + j0 + bj) * 256 + bkg * 8;

    for (int k0 = 0; k0 < 256; k0 += 32) {
        float4 f00 = *(const float4*)(hA + k0 + akg * 8);
        float4 f01 = *(const float4*)(hA + k0 + akg * 8 + 4);
        float4 f10 = *(const float4*)(hA + k0 + (akg + 2) * 8);
        float4 f11 = *(const float4*)(hA + k0 + (akg + 2) * 8 + 4);
        bf16x8 bv0 = *(const bf16x8*)(rB0 + k0);
        bf16x8 bv1 = *(const bf16x8*)(rB1 + k0);
        bf16x8 bv2 = *(const bf16x8*)(rB2 + k0);
        bf16x8 av0, av1;
        av0[0] = (__bf16)f00.x; av0[1] = (__bf16)f00.y; av0[2] = (__bf16)f00.z; av0[3] = (__bf16)f00.w;
        av0[4] = (__bf16)f01.x; av0[5] = (__bf16)f01.y; av0[6] = (__bf16)f01.z; av0[7] = (__bf16)f01.w;
        av1[0] = (__bf16)f10.x; av1[1] = (__bf16)f10.y; av1[2] = (__bf16)f10.z; av1[3] = (__bf16)f10.w;
        av1[4] = (__bf16)f11.x; av1[5] = (__bf16)f11.y; av1[6] = (__bf16)f11.z; av1[7] = (__bf16)f11.w;
        __syncthreads();
        *(bf16x8*)(ldsA + ((akg)     * 128 + arow) * 8) = av0;
        *(bf16x8*)(ldsA + ((akg + 2) * 128 + arow) * 8) = av1;
        *(bf16x8*)(ldsB + (0 * 256 + bkg * 64 + bj) * 8) = bv0;
        *(bf16x8*)(ldsB + (1 * 256 + bkg * 64 + bj) * 8) = bv1;
        *(bf16x8*)(ldsB + (2 * 256 + bkg * 64 + bj) * 8) = bv2;
        __syncthreads();

        bf16x8 af[4], bz[2], brf[2], bh[2];
        #pragma unroll
        for (int mt = 0; mt < 4; ++mt)
            af[mt] = *(const bf16x8*)(ldsA + (kgrp * 128 + rw * 64 + mt * 16 + lrow) * 8);
        #pragma unroll
        for (int jt = 0; jt < 2; ++jt) {
            int jj = cw * 32 + jt * 16 + lrow;
            bz[jt]  = *(const bf16x8*)(ldsB + (0 * 256 + kgrp * 64 + jj) * 8);
            brf[jt] = *(const bf16x8*)(ldsB + (1 * 256 + kgrp * 64 + jj) * 8);
            bh[jt]  = *(const bf16x8*)(ldsB + (2 * 256 + kgrp * 64 + jj) * 8);
        }
        #pragma unroll
        for (int mt = 0; mt < 4; ++mt)
            #pragma unroll
            for (int jt = 0; jt < 2; ++jt) {
                az[mt][jt]  = __builtin_amdgcn_mfma_f32_16x16x32_bf16(af[mt], bz[jt],  az[mt][jt],  0, 0, 0);
                ar[mt][jt]  = __builtin_amdgcn_mfma_f32_16x16x32_bf16(af[mt], brf[jt], ar[mt][jt],  0, 0, 0);
                arh[mt][jt] = __builtin_amdgcn_mfma_f32_16x16x32_bf16(af[mt], bh[jt],  arh[mt][jt], 0, 0, 0);
            }
    }

    // ---- epilogue: gates + scatter (C/D: col=lane&15, row=(lane>>4)*4+reg) ----
    #pragma unroll
    for (int mt = 0; mt < 4; ++mt) {
        int rl0 = rw * 64 + mt * 16 + kgrp * 4;
        #pragma unroll
        for (int jt = 0; jt < 2; ++jt) {
            int j = j0 + cw * 32 + jt * 16 + lrow;
            float b_z  = bi[j]       + brc[j];
            float b_r  = bi[256 + j] + brc[256 + j];
            float b_xh = bi[512 + j];
            float b_rh = brc[512 + j];
            #pragma unroll
            for (int r = 0; r < 4; ++r) {
                int rl = rl0 + r;
                size_t hoff = (size_t)idx_s[rl] * 256 + j;
                float z  = sigm_f(az[mt][jt][r] + b_z);
                float rg = sigm_f(ar[mt][jt][r] + b_r);
                float hh = tanh_f(axh[mt][jt][r] + b_xh + rg * (arh[mt][jt][r] + b_rh));
                float hp = h[hoff];
                h_out[hoff] = z * hp + (1.0f - z) * hh;
            }
        }
    }
}

// ---------------------------------------------------------------------------
extern "C" void kernel_launch(void* const* d_in, const int* in_sizes, int n_in,
                              void* d_out, int out_size, void* d_ws, size_t ws_size,
                              hipStream_t stream) {
    const float* h         = (const float*)d_in[0];
    const float* p         = (const float*)d_in[1];
    const float* X_obs     = (const float*)d_in[2];
    const float* M_obs     = (const float*)d_in[3];
    const int*   i_obs     = (const int*)  d_in[4];
    const float* w_prep    = (const float*)d_in[5];
    const float* bias_prep = (const float*)d_in[6];
    const float* gk        = (const float*)d_in[7];   // [512,768]
    const float* grk       = (const float*)d_in[8];   // [256,768]
    const float* gbi       = (const float*)d_in[9];
    const float* gbr       = (const float*)d_in[10];

    float* out    = (float*)d_out;
    float* h_out  = out;                          // [B,H]
    float* losses = out + (size_t)BB * HH;        // [N,D]

    char* ws = (char*)d_ws;
    __bf16* G  = (__bf16*)ws;                              // 32 MiB
    __bf16* Kt = (__bf16*)(ws + 33554432);                 // 768 KiB
    __bf16* Rt = (__bf16*)(ws + 33554432 + 786432);        // 384 KiB

    // independent prologue work
    copy_h_kernel<<<2048, 256, 0, stream>>>(
        (const float4*)h, (float4*)h_out, BB * HH / 4);
    transpose_w_kernel<<<dim3(8, 12), 256, 0, stream>>>(gk,  Kt, 512);
    transpose_w_kernel<<<dim3(4, 12), 256, 0, stream>>>(grk, Rt, 256);
    prep_kernel<<<(NROWS * DD) / 256, 256, 0, stream>>>(
        p, X_obs, M_obs, i_obs, w_prep, bias_prep, losses, G);

    // fused MFMA GRU
    gru_mfma_kernel<<<1024, 256, 0, stream>>>(
        G, h, i_obs, Kt, Rt, gbi, gbr, h_out);
}

// Round 9
// 269.250 us; speedup vs baseline: 2.4186x; 1.0627x over previous
//
#include <hip/hip_runtime.h>
#include <hip/hip_bf16.h>
#include <math.h>

#define NROWS 32768   // N
#define DD 32         // D
#define PPH 16        // P
#define HH 256        // H
#define BB 65536      // B
#define TWO_LOG_C 1.8378770664093453f

typedef __attribute__((ext_vector_type(8))) __bf16 bf16x8;
typedef __attribute__((ext_vector_type(4))) float f32x4;
typedef unsigned int u32;

__device__ __forceinline__ float sigm_f(float x) { return 1.0f / (1.0f + __expf(-x)); }
__device__ __forceinline__ float tanh_f(float x) { return 1.0f - 2.0f / (1.0f + __expf(2.0f * x)); }

// async global->LDS, 16B per lane; LDS dest must be wave-uniform (HW adds lane*16)
__device__ __forceinline__ void gl_lds16(const __bf16* g, __bf16* l) {
    __builtin_amdgcn_global_load_lds(
        (const __attribute__((address_space(1))) u32*)g,
        (__attribute__((address_space(3))) u32*)l, 16, 0, 0);
}

// ---------------------------------------------------------------------------
// prep: losses (f32) + G bf16 ([P,N,D] flat = GRU input [N,512] rows).
// LDS weights stored TRANSPOSED (w2[s][d]) so reads are conflict-free
// (bank = (s+d)%32; the previous [d][s] layout was a 32-way conflict).
// ---------------------------------------------------------------------------
__global__ __launch_bounds__(256) void prep_kernel(
    const float* __restrict__ p,
    const float* __restrict__ X_obs,
    const float* __restrict__ M_obs,
    const int*   __restrict__ i_obs,
    const float* __restrict__ w_prep,    // [D,4,P] flat d*64 + c*16 + q
    const float* __restrict__ bias_prep, // [D,P]
    float* __restrict__ losses_out,      // [N,D]
    __bf16* __restrict__ G)              // [N,512] bf16
{
    __shared__ float w2[64][33];   // w2[c*16+q][d]
    __shared__ float b2[16][33];   // b2[q][d]
    int tid = threadIdx.x;
    for (int i = tid; i < 2048; i += 256) w2[i & 63][i >> 6] = w_prep[i];
    for (int i = tid; i < 512; i += 256)  b2[i & 15][i >> 4] = bias_prep[i];
    __syncthreads();

    int gid = blockIdx.x * 256 + tid;
    int n = gid >> 5;
    int d = gid & 31;
    int idx = i_obs[n];

    float mean   = p[idx * (2 * DD) + d];
    float logvar = p[idx * (2 * DD) + DD + d];
    float x      = X_obs[gid];
    float m      = M_obs[gid];

    float inv_sigma = __expf(-0.5f * logvar);
    float err = (x - mean) * inv_sigma;
    losses_out[gid] = 0.5f * ((err * err + logvar + TWO_LOG_C) * m);

    #pragma unroll
    for (int q = 0; q < PPH; ++q) {
        float v = x      * w2[q][d]
                + mean   * w2[16 + q][d]
                + logvar * w2[32 + q][d]
                + err    * w2[48 + q][d]
                + b2[q][d];
        v = fmaxf(v, 0.0f) * m;
        G[(size_t)q * (NROWS * DD) + gid] = (__bf16)v;
    }
}

// ---------------------------------------------------------------------------
// scatter mask: mask[r]=1 iff r in i_obs. Lets copy skip rows gru overwrites
// (write-disjoint -> order-independent, and saves ~64MB traffic).
// ---------------------------------------------------------------------------
__global__ __launch_bounds__(256) void mask_zero_kernel(u32* __restrict__ mask32) {
    mask32[blockIdx.x * 256 + threadIdx.x] = 0;   // 16384 u32 = 64KB
}
__global__ __launch_bounds__(256) void mask_set_kernel(
    const int* __restrict__ i_obs, unsigned char* __restrict__ mask) {
    mask[i_obs[blockIdx.x * 256 + threadIdx.x]] = 1;
}
__global__ __launch_bounds__(256) void copy_h_masked_kernel(
    const float4* __restrict__ h, const unsigned char* __restrict__ mask,
    float4* __restrict__ out, int n4)
{
    int i = blockIdx.x * 256 + threadIdx.x;
    int stride = gridDim.x * 256;
    for (; i < n4; i += stride) {
        int row = i >> 6;                  // 64 float4 per 256-f32 row
        if (!mask[row]) out[i] = h[i];
    }
}

// ---------------------------------------------------------------------------
// gather h[i_obs] -> bf16 Hb[N][256] (feeds phase-2 global_load_lds staging)
// ---------------------------------------------------------------------------
__global__ __launch_bounds__(256) void hgather_kernel(
    const float* __restrict__ h, const int* __restrict__ i_obs,
    __bf16* __restrict__ Hb)
{
    int gid = blockIdx.x * 256 + threadIdx.x;    // N*32
    int n = gid >> 5, c = gid & 31;
    const float* src = h + (size_t)i_obs[n] * 256 + c * 8;
    float4 a = ((const float4*)src)[0];
    float4 b = ((const float4*)src)[1];
    bf16x8 v;
    v[0] = (__bf16)a.x; v[1] = (__bf16)a.y; v[2] = (__bf16)a.z; v[3] = (__bf16)a.w;
    v[4] = (__bf16)b.x; v[5] = (__bf16)b.y; v[6] = (__bf16)b.z; v[7] = (__bf16)b.w;
    *(bf16x8*)(Hb + (size_t)n * 256 + c * 8) = v;
}

// ---------------------------------------------------------------------------
// weight transpose + f32->bf16: dst[j][k] = (bf16)src[k][j]
// ---------------------------------------------------------------------------
__global__ __launch_bounds__(256) void transpose_w_kernel(
    const float* __restrict__ src, __bf16* __restrict__ dst, int K)
{
    __shared__ float t[64][65];
    int k0 = blockIdx.x * 64;
    int j0 = blockIdx.y * 64;
    int tx = threadIdx.x & 63, ty = threadIdx.x >> 6;
    #pragma unroll
    for (int i = 0; i < 16; ++i) {
        int k = ty * 16 + i;
        t[k][tx] = src[(size_t)(k0 + k) * 768 + j0 + tx];
    }
    __syncthreads();
    #pragma unroll
    for (int i = 0; i < 16; ++i) {
        int j = ty * 16 + i;
        dst[(size_t)(j0 + j) * K + k0 + tx] = (__bf16)t[tx][j];
    }
}

// ---------------------------------------------------------------------------
// fused GRU via bf16 MFMA, async-staged double-buffered pipeline.
// Block: 128 rows x 64 h-cols, 4 waves (2x2), wave tile 64x32 (Mrep=4,Nrep=2).
// 24 unified K-steps (16 of G@Kt, 8 of Hb@Rt), per step:
//   stage(t+1) via 5x global_load_lds/wave -> ds_read frags(t) -> 24 MFMA
//   -> s_waitcnt vmcnt(0) -> barrier  (counted-load 2-phase template)
// ---------------------------------------------------------------------------
#define A_EL 4096   // [4 kgrp][128 row][8]
#define B_EL 6144   // [3 mat][4 kgrp][64 j][8]

struct StageCtx {
    const __bf16 *G, *Hb, *Kt, *Rt;
    int i0, j0, wave, lane;
};

__device__ __forceinline__ void stage_step(int t, const StageCtx& c,
                                           __bf16* ldsA, __bf16* ldsB) {
    const bool ph1 = t < 16;
    const int k0 = (ph1 ? t : (t - 16)) * 32;
    const int Kd = ph1 ? 512 : 256;
    const __bf16* Asrc = ph1 ? c.G : c.Hb;
    const __bf16* Bsrc = ph1 ? c.Kt : c.Rt;
    __bf16* dA = ldsA + (t & 1) * A_EL;
    __bf16* dB = ldsB + (t & 1) * B_EL;
    #pragma unroll
    for (int s = 0; s < 5; ++s) {
        int u = c.wave * 5 + s;
        if (u < 8) {
            int sA = u * 64 + c.lane;
            int kg = sA >> 7, row = sA & 127;
            gl_lds16(Asrc + (size_t)(c.i0 + row) * Kd + k0 + kg * 8,
                     dA + u * 64 * 8);
        } else {
            int sB = (u - 8) * 64 + c.lane;
            int mat = sB >> 8, w = sB & 255;
            int bkg = w >> 6, bj = w & 63;
            gl_lds16(Bsrc + (size_t)(mat * 256 + c.j0 + bj) * Kd + k0 + bkg * 8,
                     dB + (u - 8) * 64 * 8);
        }
    }
}

__device__ __forceinline__ void compute_step(
    const __bf16* cA, const __bf16* cB,
    int kgrp, int lrow, int rw, int cw,
    f32x4 (&az)[4][2], f32x4 (&ar)[4][2], f32x4 (&ah)[4][2])
{
    bf16x8 af[4], bz[2], brf[2], bh[2];
    #pragma unroll
    for (int mt = 0; mt < 4; ++mt)
        af[mt] = *(const bf16x8*)(cA + (kgrp * 128 + rw * 64 + mt * 16 + lrow) * 8);
    #pragma unroll
    for (int jt = 0; jt < 2; ++jt) {
        int jj = cw * 32 + jt * 16 + lrow;
        bz[jt]  = *(const bf16x8*)(cB + (0 * 256 + kgrp * 64 + jj) * 8);
        brf[jt] = *(const bf16x8*)(cB + (1 * 256 + kgrp * 64 + jj) * 8);
        bh[jt]  = *(const bf16x8*)(cB + (2 * 256 + kgrp * 64 + jj) * 8);
    }
    #pragma unroll
    for (int mt = 0; mt < 4; ++mt)
        #pragma unroll
        for (int jt = 0; jt < 2; ++jt) {
            az[mt][jt] = __builtin_amdgcn_mfma_f32_16x16x32_bf16(af[mt], bz[jt],  az[mt][jt], 0, 0, 0);
            ar[mt][jt] = __builtin_amdgcn_mfma_f32_16x16x32_bf16(af[mt], brf[jt], ar[mt][jt], 0, 0, 0);
            ah[mt][jt] = __builtin_amdgcn_mfma_f32_16x16x32_bf16(af[mt], bh[jt],  ah[mt][jt], 0, 0, 0);
        }
}

__global__ __launch_bounds__(256, 2) void gru_mfma_kernel(
    const __bf16* __restrict__ G,     // [N,512]
    const __bf16* __restrict__ Hb,    // [N,256] = bf16(h[i_obs])
    const float*  __restrict__ h,     // [B,256]
    const int*    __restrict__ i_obs,
    const __bf16* __restrict__ Kt,    // [768][512]
    const __bf16* __restrict__ Rt,    // [768][256]
    const float*  __restrict__ bi,
    const float*  __restrict__ brc,
    float* __restrict__ h_out)        // [B,256]
{
    __shared__ __bf16 ldsA[2][A_EL];
    __shared__ __bf16 ldsB[2][B_EL];
    __shared__ int idx_s[128];

    const int tid  = threadIdx.x;
    const int lane = tid & 63;
    const int wave = tid >> 6;
    const int lrow = lane & 15;
    const int kgrp = lane >> 4;
    const int rw = wave >> 1;
    const int cw = wave & 1;

    // XCD-aware swizzle (1024 blocks, 8 XCDs)
    int bid = blockIdx.x;
    int swz = (bid & 7) * 128 + (bid >> 3);
    const int i0 = (swz >> 2) * 128;
    const int j0 = (swz & 3) * 64;

    if (tid < 128) idx_s[tid] = i_obs[i0 + tid];

    f32x4 az[4][2], ar[4][2], axh[4][2], arh[4][2];
    const f32x4 zero4 = {0.f, 0.f, 0.f, 0.f};
    #pragma unroll
    for (int m = 0; m < 4; ++m)
        #pragma unroll
        for (int j = 0; j < 2; ++j) {
            az[m][j] = zero4; ar[m][j] = zero4; axh[m][j] = zero4; arh[m][j] = zero4;
        }

    StageCtx ctx{G, Hb, Kt, Rt, i0, j0, wave, lane};

    stage_step(0, ctx, &ldsA[0][0], &ldsB[0][0]);
    asm volatile("s_waitcnt vmcnt(0) lgkmcnt(0)" ::: "memory");
    __builtin_amdgcn_s_barrier();

    for (int t = 0; t < 16; ++t) {                     // phase 1: G @ Kt
        stage_step(t + 1, ctx, &ldsA[0][0], &ldsB[0][0]);
        compute_step(&ldsA[t & 1][0], &ldsB[t & 1][0], kgrp, lrow, rw, cw,
                     az, ar, axh);
        asm volatile("s_waitcnt vmcnt(0)" ::: "memory");
        __builtin_amdgcn_s_barrier();
    }
    for (int t = 16; t < 24; ++t) {                    // phase 2: Hb @ Rt
        if (t < 23) stage_step(t + 1, ctx, &ldsA[0][0], &ldsB[0][0]);
        compute_step(&ldsA[t & 1][0], &ldsB[t & 1][0], kgrp, lrow, rw, cw,
                     az, ar, arh);
        asm volatile("s_waitcnt vmcnt(0)" ::: "memory");
        __builtin_amdgcn_s_barrier();
    }

    // epilogue: gates + scatter (C/D: col=lane&15, row=(lane>>4)*4+reg)
    #pragma unroll
    for (int mt = 0; mt < 4; ++mt) {
        int rl0 = rw * 64 + mt * 16 + kgrp * 4;
        #pragma unroll
        for (int jt = 0; jt < 2; ++jt) {
            int j = j0 + cw * 32 + jt * 16 + lrow;
            float b_z  = bi[j]       + brc[j];
            float b_r  = bi[256 + j] + brc[256 + j];
            float b_xh = bi[512 + j];
            float b_rh = brc[512 + j];
            #pragma unroll
            for (int r = 0; r < 4; ++r) {
                size_t hoff = (size_t)idx_s[rl0 + r] * 256 + j;
                float z  = sigm_f(az[mt][jt][r] + b_z);
                float rg = sigm_f(ar[mt][jt][r] + b_r);
                float hh = tanh_f(axh[mt][jt][r] + b_xh + rg * (arh[mt][jt][r] + b_rh));
                float hp = h[hoff];
                h_out[hoff] = z * hp + (1.0f - z) * hh;
            }
        }
    }
}

// ---------------------------------------------------------------------------
extern "C" void kernel_launch(void* const* d_in, const int* in_sizes, int n_in,
                              void* d_out, int out_size, void* d_ws, size_t ws_size,
                              hipStream_t stream) {
    const float* h         = (const float*)d_in[0];
    const float* p         = (const float*)d_in[1];
    const float* X_obs     = (const float*)d_in[2];
    const float* M_obs     = (const float*)d_in[3];
    const int*   i_obs     = (const int*)  d_in[4];
    const float* w_prep    = (const float*)d_in[5];
    const float* bias_prep = (const float*)d_in[6];
    const float* gk        = (const float*)d_in[7];
    const float* grk       = (const float*)d_in[8];
    const float* gbi       = (const float*)d_in[9];
    const float* gbr       = (const float*)d_in[10];

    float* out    = (float*)d_out;
    float* h_out  = out;
    float* losses = out + (size_t)BB * HH;

    char* ws = (char*)d_ws;
    __bf16* G    = (__bf16*)ws;                        // 32 MiB
    __bf16* Kt   = (__bf16*)(ws + 33554432);           // 768 KiB
    __bf16* Rt   = (__bf16*)(ws + 34340864);           // 384 KiB
    __bf16* Hb   = (__bf16*)(ws + 34734080);           // 16 MiB
    unsigned char* mask = (unsigned char*)(ws + 51511296);  // 64 KiB

    mask_zero_kernel<<<64, 256, 0, stream>>>((u32*)mask);
    mask_set_kernel<<<NROWS / 256, 256, 0, stream>>>(i_obs, mask);
    transpose_w_kernel<<<dim3(8, 12), 256, 0, stream>>>(gk,  Kt, 512);
    transpose_w_kernel<<<dim3(4, 12), 256, 0, stream>>>(grk, Rt, 256);
    hgather_kernel<<<NROWS * 32 / 256, 256, 0, stream>>>(h, i_obs, Hb);
    prep_kernel<<<(NROWS * DD) / 256, 256, 0, stream>>>(
        p, X_obs, M_obs, i_obs, w_prep, bias_prep, losses, G);
    copy_h_masked_kernel<<<2048, 256, 0, stream>>>(
        (const float4*)h, mask, (float4*)h_out, BB * HH / 4);
    gru_mfma_kernel<<<1024, 256, 0, stream>>>(
        G, Hb, h, i_obs, Kt, Rt, gbi, gbr, h_out);
}

// Round 10
// 218.509 us; speedup vs baseline: 2.9803x; 1.2322x over previous
//
#include <hip/hip_runtime.h>
#include <hip/hip_bf16.h>
#include <math.h>

#define NROWS 32768   // N
#define DD 32         // D
#define PPH 16        // P
#define HH 256        // H
#define BB 65536      // B
#define TWO_LOG_C 1.8378770664093453f

typedef __attribute__((ext_vector_type(8))) __bf16 bf16x8;
typedef __attribute__((ext_vector_type(4))) float f32x4;
typedef unsigned int u32;

__device__ __forceinline__ float sigm_f(float x) { return 1.0f / (1.0f + __expf(-x)); }
__device__ __forceinline__ float tanh_f(float x) { return 1.0f - 2.0f / (1.0f + __expf(2.0f * x)); }

// async global->LDS, 16B per lane; LDS dest wave-uniform (HW adds lane*16)
__device__ __forceinline__ void gl_lds16(const __bf16* g, __bf16* l) {
    __builtin_amdgcn_global_load_lds(
        (const __attribute__((address_space(1))) u32*)g,
        (__attribute__((address_space(3))) u32*)l, 16, 0, 0);
}

// ---------------------------------------------------------------------------
// pre_kernel: ALL prologue work fused into one dispatch (launch overhead was
// ~18us/dispatch at 8 dispatches).
//  blocks 0..4095   : prep (losses + G bf16) + Hb gather + h->h_out copy
//  blocks 4096..4239: weight transpose+cvt (96 Kt tiles, 48 Rt tiles)
// ---------------------------------------------------------------------------
__global__ __launch_bounds__(256) void pre_kernel(
    const float* __restrict__ h,          // [B,256]
    const float* __restrict__ p,          // [B,64]
    const float* __restrict__ X_obs,      // [N,32]
    const float* __restrict__ M_obs,      // [N,32]
    const int*   __restrict__ i_obs,      // [N]
    const float* __restrict__ w_prep,     // [D,4,P]
    const float* __restrict__ bias_prep,  // [D,P]
    const float* __restrict__ gk,         // [512,768]
    const float* __restrict__ grk,        // [256,768]
    float* __restrict__ losses,           // [N,32]
    __bf16* __restrict__ G,               // [N,512]
    __bf16* __restrict__ Hb,              // [N,256]
    __bf16* __restrict__ Kt,              // [768][512]
    __bf16* __restrict__ Rt,              // [768][256]
    float* __restrict__ h_out)            // [B,256]
{
    __shared__ float arena[4160];         // 16640B, aliased per branch
    const int bid = blockIdx.x;
    const int tid = threadIdx.x;

    if (bid < 4096) {
        // ---- prep branch ----
        float (*w2)[33] = (float(*)[33])arena;              // [64][33]  (s,d)
        float (*b2)[33] = (float(*)[33])(arena + 64 * 33);  // [16][33]  (q,d)
        for (int i = tid; i < 2048; i += 256) w2[i & 63][i >> 6] = w_prep[i];
        for (int i = tid; i < 512; i += 256)  b2[i & 15][i >> 4] = bias_prep[i];
        __syncthreads();

        const int gid = bid * 256 + tid;      // 0 .. N*32-1
        const int n = gid >> 5;
        const int d = gid & 31;
        const int idx = i_obs[n];

        float mean   = p[idx * 64 + d];
        float logvar = p[idx * 64 + 32 + d];
        float x      = X_obs[gid];
        float m      = M_obs[gid];

        float inv_sigma = __expf(-0.5f * logvar);
        float err = (x - mean) * inv_sigma;
        losses[gid] = 0.5f * ((err * err + logvar + TWO_LOG_C) * m);

        #pragma unroll
        for (int q = 0; q < PPH; ++q) {
            float v = x      * w2[q][d]
                    + mean   * w2[16 + q][d]
                    + logvar * w2[32 + q][d]
                    + err    * w2[48 + q][d]
                    + b2[q][d];
            v = fmaxf(v, 0.0f) * m;
            G[(size_t)q * (NROWS * DD) + gid] = (__bf16)v;
        }

        // ---- Hb gather: thread covers h[i_obs[n]][d*8 .. d*8+7] ----
        const float* hsrc = h + (size_t)idx * 256 + d * 8;
        float4 a = ((const float4*)hsrc)[0];
        float4 b = ((const float4*)hsrc)[1];
        bf16x8 v8;
        v8[0] = (__bf16)a.x; v8[1] = (__bf16)a.y; v8[2] = (__bf16)a.z; v8[3] = (__bf16)a.w;
        v8[4] = (__bf16)b.x; v8[5] = (__bf16)b.y; v8[6] = (__bf16)b.z; v8[7] = (__bf16)b.w;
        *(bf16x8*)(Hb + (size_t)n * 256 + d * 8) = v8;

        // ---- h -> h_out full copy (4 float4/thread, gru overwrites i_obs rows) ----
        const float4* hf4 = (const float4*)h;
        float4* of4 = (float4*)h_out;
        #pragma unroll
        for (int k2 = 0; k2 < 4; ++k2) {
            int i4 = gid + k2 * 1048576;     // covers BB*HH/4 = 4194304
            of4[i4] = hf4[i4];
        }
    } else {
        // ---- weight transpose branch: dst[j][k] = (bf16)src[k][j] ----
        float (*t)[65] = (float(*)[65])arena;   // [64][65]
        int b = bid - 4096;
        const float* src; __bf16* dst; int K, k0, j0;
        if (b < 96) { src = gk;  dst = Kt; K = 512; k0 = (b & 7) * 64; j0 = (b >> 3) * 64; }
        else { b -= 96; src = grk; dst = Rt; K = 256; k0 = (b & 3) * 64; j0 = (b >> 2) * 64; }
        int tx = tid & 63, ty = tid >> 6;
        #pragma unroll
        for (int i = 0; i < 16; ++i) {
            int k = ty * 16 + i;
            t[k][tx] = src[(size_t)(k0 + k) * 768 + j0 + tx];
        }
        __syncthreads();
        #pragma unroll
        for (int i = 0; i < 16; ++i) {
            int j = ty * 16 + i;
            dst[(size_t)(j0 + j) * K + k0 + tx] = (__bf16)t[tx][j];
        }
    }
}

// ---------------------------------------------------------------------------
// fused GRU via bf16 MFMA — COALESCED staging + counted vmcnt.
// Block 128 rows x 64 j (x3 mats), BK=32, 4 waves (2x2), wave tile 64x32.
// LDS per buffer: A[128 rows][32k] (8KB) + B[192 rows][32k] (12KB), 2 buffers.
// Staging: wave-load u covers 16 rows x 64B contiguous LDS; global source
// pre-swizzled kg = slot ^ ((row>>1)&3) so ds_read_b128 frags are
// bank-balanced while global segments stay 64B-coalesced (16 sectors/load
// vs 64 lines before — the round-9 bottleneck).
// Pipeline: stage(0),stage(1); loop t: vmcnt(5) [t done, t+1 in flight];
// barrier; compute(t); barrier; stage(t+2). vmcnt(0) only at t=23.
// ---------------------------------------------------------------------------
#define A_EL 4096   // 128*32 bf16
#define B_EL 6144   // 192*32 bf16

struct StageCtx {
    const __bf16 *G, *Hb, *Kt, *Rt;
    int i0, j0, wave, lane;
};

__device__ __forceinline__ void stage_step(int t, const StageCtx& c,
                                           __bf16* ldsA, __bf16* ldsB) {
    const bool ph1 = t < 16;
    const int k0 = (ph1 ? t : (t - 16)) * 32;
    const int Kd = ph1 ? 512 : 256;
    const __bf16* Asrc = ph1 ? c.G : c.Hb;
    const __bf16* Bsrc = ph1 ? c.Kt : c.Rt;
    __bf16* dA = ldsA + (t & 1) * A_EL;
    __bf16* dB = ldsB + (t & 1) * B_EL;
    const int rsub  = c.lane >> 2;    // 0..15 row within unit
    const int sslot = c.lane & 3;     // 16B slot within row
    #pragma unroll
    for (int s = 0; s < 5; ++s) {
        int u = c.wave * 5 + s;       // 0..19
        if (u < 8) {                  // A: 8 units x 16 rows = 128 rows
            int row = u * 16 + rsub;
            int kg = sslot ^ ((row >> 1) & 3);
            gl_lds16(Asrc + (size_t)(c.i0 + row) * Kd + k0 + kg * 8,
                     dA + u * 512);
        } else {                      // B: 12 units x 16 rows = 192 rows
            int v = u - 8;
            int br = v * 16 + rsub;
            int kg = sslot ^ ((br >> 1) & 3);
            int mat = br >> 6, jr = br & 63;
            gl_lds16(Bsrc + (size_t)(mat * 256 + c.j0 + jr) * Kd + k0 + kg * 8,
                     dB + v * 512);
        }
    }
}

__device__ __forceinline__ void compute_step(
    const __bf16* cA, const __bf16* cB,
    int kgrp, int lrow, int rw, int cw,
    f32x4 (&az)[4][2], f32x4 (&ar)[4][2], f32x4 (&ah)[4][2])
{
    bf16x8 af[4], bz[2], brf[2], bh[2];
    #pragma unroll
    for (int mt = 0; mt < 4; ++mt) {
        int r = rw * 64 + mt * 16 + lrow;
        af[mt] = *(const bf16x8*)(cA + r * 32 + (kgrp ^ ((r >> 1) & 3)) * 8);
    }
    #pragma unroll
    for (int jt = 0; jt < 2; ++jt) {
        int jj = cw * 32 + jt * 16 + lrow;
        int b0 = jj, b1 = 64 + jj, b2r = 128 + jj;
        bz[jt]  = *(const bf16x8*)(cB + b0  * 32 + (kgrp ^ ((b0  >> 1) & 3)) * 8);
        brf[jt] = *(const bf16x8*)(cB + b1  * 32 + (kgrp ^ ((b1  >> 1) & 3)) * 8);
        bh[jt]  = *(const bf16x8*)(cB + b2r * 32 + (kgrp ^ ((b2r >> 1) & 3)) * 8);
    }
    #pragma unroll
    for (int mt = 0; mt < 4; ++mt)
        #pragma unroll
        for (int jt = 0; jt < 2; ++jt) {
            az[mt][jt] = __builtin_amdgcn_mfma_f32_16x16x32_bf16(af[mt], bz[jt],  az[mt][jt], 0, 0, 0);
            ar[mt][jt] = __builtin_amdgcn_mfma_f32_16x16x32_bf16(af[mt], brf[jt], ar[mt][jt], 0, 0, 0);
            ah[mt][jt] = __builtin_amdgcn_mfma_f32_16x16x32_bf16(af[mt], bh[jt],  ah[mt][jt], 0, 0, 0);
        }
}

__global__ __launch_bounds__(256, 2) void gru_mfma_kernel(
    const __bf16* __restrict__ G,     // [N,512]
    const __bf16* __restrict__ Hb,    // [N,256]
    const float*  __restrict__ h,     // [B,256]
    const int*    __restrict__ i_obs,
    const __bf16* __restrict__ Kt,    // [768][512]
    const __bf16* __restrict__ Rt,    // [768][256]
    const float*  __restrict__ bi,
    const float*  __restrict__ brc,
    float* __restrict__ h_out)        // [B,256]
{
    __shared__ __bf16 ldsA[2][A_EL];
    __shared__ __bf16 ldsB[2][B_EL];
    __shared__ int idx_s[128];

    const int tid  = threadIdx.x;
    const int lane = tid & 63;
    const int wave = tid >> 6;
    const int lrow = lane & 15;
    const int kgrp = lane >> 4;
    const int rw = wave >> 1;
    const int cw = wave & 1;

    // XCD-aware swizzle (1024 blocks, 8 XCDs; bijective since 1024%8==0)
    int bid = blockIdx.x;
    int swz = (bid & 7) * 128 + (bid >> 3);
    const int i0 = (swz >> 2) * 128;
    const int j0 = (swz & 3) * 64;

    if (tid < 128) idx_s[tid] = i_obs[i0 + tid];
    asm volatile("s_waitcnt lgkmcnt(0)" ::: "memory");  // idx_s visible pre-barrier

    f32x4 az[4][2], ar[4][2], axh[4][2], arh[4][2];
    const f32x4 zero4 = {0.f, 0.f, 0.f, 0.f};
    #pragma unroll
    for (int m = 0; m < 4; ++m)
        #pragma unroll
        for (int j = 0; j < 2; ++j) {
            az[m][j] = zero4; ar[m][j] = zero4; axh[m][j] = zero4; arh[m][j] = zero4;
        }

    StageCtx ctx{G, Hb, Kt, Rt, i0, j0, wave, lane};

    stage_step(0, ctx, &ldsA[0][0], &ldsB[0][0]);
    stage_step(1, ctx, &ldsA[0][0], &ldsB[0][0]);

    #pragma unroll
    for (int t = 0; t < 16; ++t) {                     // phase 1: G @ Kt
        asm volatile("s_waitcnt vmcnt(5)" ::: "memory");
        __builtin_amdgcn_s_barrier();
        compute_step(&ldsA[t & 1][0], &ldsB[t & 1][0], kgrp, lrow, rw, cw,
                     az, ar, axh);
        __builtin_amdgcn_s_barrier();
        stage_step(t + 2, ctx, &ldsA[0][0], &ldsB[0][0]);
    }
    #pragma unroll
    for (int t = 16; t < 24; ++t) {                    // phase 2: Hb @ Rt
        if (t < 23) { asm volatile("s_waitcnt vmcnt(5)" ::: "memory"); }
        else        { asm volatile("s_waitcnt vmcnt(0)" ::: "memory"); }
        __builtin_amdgcn_s_barrier();
        compute_step(&ldsA[t & 1][0], &ldsB[t & 1][0], kgrp, lrow, rw, cw,
                     az, ar, arh);
        __builtin_amdgcn_s_barrier();
        if (t + 2 < 24) stage_step(t + 2, ctx, &ldsA[0][0], &ldsB[0][0]);
    }

    // epilogue: gates + scatter (C/D: col=lane&15, row=(lane>>4)*4+reg)
    #pragma unroll
    for (int mt = 0; mt < 4; ++mt) {
        int rl0 = rw * 64 + mt * 16 + kgrp * 4;
        #pragma unroll
        for (int jt = 0; jt < 2; ++jt) {
            int j = j0 + cw * 32 + jt * 16 + lrow;
            float b_z  = bi[j]       + brc[j];
            float b_r  = bi[256 + j] + brc[256 + j];
            float b_xh = bi[512 + j];
            float b_rh = brc[512 + j];
            #pragma unroll
            for (int r = 0; r < 4; ++r) {
                size_t hoff = (size_t)idx_s[rl0 + r] * 256 + j;
                float z  = sigm_f(az[mt][jt][r] + b_z);
                float rg = sigm_f(ar[mt][jt][r] + b_r);
                float hh = tanh_f(axh[mt][jt][r] + b_xh + rg * (arh[mt][jt][r] + b_rh));
                float hp = h[hoff];
                h_out[hoff] = z * hp + (1.0f - z) * hh;
            }
        }
    }
}

// ---------------------------------------------------------------------------
extern "C" void kernel_launch(void* const* d_in, const int* in_sizes, int n_in,
                              void* d_out, int out_size, void* d_ws, size_t ws_size,
                              hipStream_t stream) {
    const float* h         = (const float*)d_in[0];
    const float* p         = (const float*)d_in[1];
    const float* X_obs     = (const float*)d_in[2];
    const float* M_obs     = (const float*)d_in[3];
    const int*   i_obs     = (const int*)  d_in[4];
    const float* w_prep    = (const float*)d_in[5];
    const float* bias_prep = (const float*)d_in[6];
    const float* gk        = (const float*)d_in[7];
    const float* grk       = (const float*)d_in[8];
    const float* gbi       = (const float*)d_in[9];
    const float* gbr       = (const float*)d_in[10];

    float* out    = (float*)d_out;
    float* h_out  = out;
    float* losses = out + (size_t)BB * HH;

    char* ws = (char*)d_ws;
    __bf16* G  = (__bf16*)ws;                          // 32 MiB
    __bf16* Kt = (__bf16*)(ws + 33554432);             // 768 KiB
    __bf16* Rt = (__bf16*)(ws + 34340864);             // 384 KiB
    __bf16* Hb = (__bf16*)(ws + 34734080);             // 16 MiB

    pre_kernel<<<4240, 256, 0, stream>>>(
        h, p, X_obs, M_obs, i_obs, w_prep, bias_prep, gk, grk,
        losses, G, Hb, Kt, Rt, h_out);

    gru_mfma_kernel<<<1024, 256, 0, stream>>>(
        G, Hb, h, i_obs, Kt, Rt, gbi, gbr, h_out);
}